// Round 1
// baseline (598.241 us; speedup 1.0000x reference)
//
#include <hip/hip_runtime.h>
#include <hip/hip_bf16.h>

// Sizes
#define B_ 8
#define S_ 128
#define D_ 512
#define N_ 64
#define H_ 128

// ws offsets (in floats)
#define OFF_WX      0
#define OFF_PX      65536
#define OFF_X       131072
#define OFF_GXF     655360
#define OFF_GXR     1179648
#define OFF_HF      1703936
#define OFF_HR      1835008
#define OFF_GX2     1966080
#define OFF_WIHTQ_F 2490368
#define OFF_WIHTQ_R 2752512
#define OFF_WIHT2Q  3014656
#define OFF_WHHT_F  3145728
#define OFF_WHHT_R  3211264
#define OFF_WHHT2   3276800
#define OFF_BIASF   3342336
#define OFF_BIASR   3342848
#define OFF_BIAS2   3343360

__device__ __forceinline__ float rlane(float v, int l) {
    return __int_as_float(__builtin_amdgcn_readlane(__float_as_int(v), l));
}
__device__ __forceinline__ float sigf(float x) {
    return 1.0f / (1.0f + expf(-x));
}

// ---------------- K0: weight transposes + bias sums ----------------
__global__ __launch_bounds__(256) void k_prep(
    const float* __restrict__ Wih_f, const float* __restrict__ Wih_r,
    const float* __restrict__ Wih2,
    const float* __restrict__ Whh_f, const float* __restrict__ Whh_r,
    const float* __restrict__ Whh2,
    const float* __restrict__ bih_f, const float* __restrict__ bhh_f,
    const float* __restrict__ bih_r, const float* __restrict__ bhh_r,
    const float* __restrict__ bih2, const float* __restrict__ bhh2,
    float* __restrict__ wihTq_f, float* __restrict__ wihTq_r,
    float* __restrict__ wihT2q,
    float* __restrict__ whhT_f, float* __restrict__ whhT_r,
    float* __restrict__ whhT2,
    float* __restrict__ biasf, float* __restrict__ biasr, float* __restrict__ bias2)
{
    int idx = blockIdx.x * blockDim.x + threadIdx.x;
    int stride = gridDim.x * blockDim.x;
    // Wih (512x512) -> quad-blocked transposed: out[q*2048 + j*4 + e] = in[j*512 + 4q+e]
    for (int o = idx; o < 262144; o += stride) {
        int q = o >> 11, rem = o & 2047, j = rem >> 2, e = rem & 3;
        int k = 4 * q + e;
        wihTq_f[o] = Wih_f[j * 512 + k];
        wihTq_r[o] = Wih_r[j * 512 + k];
    }
    // Wih2 (512x256)
    for (int o = idx; o < 131072; o += stride) {
        int q = o >> 11, rem = o & 2047, j = rem >> 2, e = rem & 3;
        int k = 4 * q + e;
        wihT2q[o] = Wih2[j * 256 + k];
    }
    // Whh (512x128) -> plain transpose [k][512]
    for (int o = idx; o < 65536; o += stride) {
        int k = o >> 9, j = o & 511;
        whhT_f[o] = Whh_f[j * 128 + k];
        whhT_r[o] = Whh_r[j * 128 + k];
        whhT2[o]  = Whh2[j * 128 + k];
    }
    if (idx < 512) {
        biasf[idx] = bih_f[idx] + bhh_f[idx];
        biasr[idx] = bih_r[idx] + bhh_r[idx];
        bias2[idx] = bih2[idx] + bhh2[idx];
    }
}

// ---------------- K1: Wx = A@Wx_W^T + b ; Px = A@Wxh_W^T + b ----------------
__global__ __launch_bounds__(64) void k_qk(
    const float* __restrict__ A,
    const float* __restrict__ WxW, const float* __restrict__ Wxb,
    const float* __restrict__ WxhW, const float* __restrict__ Wxhb,
    float* __restrict__ WX, float* __restrict__ PX)
{
    int bs = blockIdx.x;
    int n = threadIdx.x;
    const float* arow = A + bs * 512;
    const float* wr = WxW + n * 512;
    const float* pr = WxhW + n * 512;
    float aw = 0.f, ap = 0.f;
    #pragma unroll 8
    for (int k = 0; k < 512; k += 4) {
        float4 a = *(const float4*)(arow + k);   // uniform -> scalar loads
        float4 w = *(const float4*)(wr + k);
        float4 p = *(const float4*)(pr + k);
        aw += a.x * w.x + a.y * w.y + a.z * w.z + a.w * w.w;
        ap += a.x * p.x + a.y * p.y + a.z * p.z + a.w * p.w;
    }
    WX[bs * 64 + n] = aw + Wxb[n];
    PX[bs * 64 + n] = ap + Wxhb[n];
}

// ---------------- K2: attention scores + X = scores@A ----------------
__global__ __launch_bounds__(256) void k_attn(
    const float* __restrict__ A,
    const float* __restrict__ WX, const float* __restrict__ PX,
    const float* __restrict__ AttW, const float* __restrict__ Attb,
    float* __restrict__ X)
{
    int b = blockIdx.x >> 5;
    int i0 = (blockIdx.x & 31) * 4;
    int tid = threadIdx.x;
    __shared__ float px[128][65];
    __shared__ float wx[4][64];
    __shared__ float aw[64];
    __shared__ float sc[128][4];

    const float* pxg = PX + b * 8192;
    for (int q = tid; q < 2048; q += 256) {
        int j = q >> 4, nq = (q & 15) * 4;
        float4 v = *(const float4*)(pxg + j * 64 + nq);
        px[j][nq] = v.x; px[j][nq + 1] = v.y; px[j][nq + 2] = v.z; px[j][nq + 3] = v.w;
    }
    if (tid < 64) {
        aw[tid] = AttW[tid];
        #pragma unroll
        for (int ii = 0; ii < 4; ii++)
            wx[ii][tid] = WX[b * 8192 + (i0 + ii) * 64 + tid];
    }
    __syncthreads();
    float attb = Attb[0];
    for (int p = tid; p < 512; p += 256) {
        int ii = p >> 7, j = p & 127;
        float acc = 0.f;
        #pragma unroll 4
        for (int n = 0; n < 64; n++) {
            acc += tanhf(px[j][n] + wx[ii][n]) * aw[n];
        }
        sc[j][ii] = sigf(acc + attb);
    }
    __syncthreads();
    // X phase: 2 i-values per thread, 4 d's each
    int half = tid >> 7;
    int dq = (tid & 127) * 4;
    int ii0 = half * 2;
    float4 acc0 = {0, 0, 0, 0}, acc1 = {0, 0, 0, 0};
    const float* Ab = A + b * 65536;
    for (int j = 0; j < 128; j++) {
        float4 av = *(const float4*)(Ab + j * 512 + dq);
        float s0 = sc[j][ii0], s1 = sc[j][ii0 + 1];
        acc0.x += av.x * s0; acc0.y += av.y * s0; acc0.z += av.z * s0; acc0.w += av.w * s0;
        acc1.x += av.x * s1; acc1.y += av.y * s1; acc1.z += av.z * s1; acc1.w += av.w * s1;
    }
    float* Xp = X + b * 65536;
    *(float4*)(Xp + (i0 + ii0) * 512 + dq) = acc0;
    *(float4*)(Xp + (i0 + ii0 + 1) * 512 + dq) = acc1;
}

// ---------------- K3: gxf = X@Wih_f^T + bias ; gxr (time-reversed rows) ----------------
__global__ __launch_bounds__(512) void k_gx(
    const float* __restrict__ X,
    const float* __restrict__ wihTq_f, const float* __restrict__ wihTq_r,
    const float* __restrict__ biasf, const float* __restrict__ biasr,
    float* __restrict__ GXF, float* __restrict__ GXR)
{
    int r0 = blockIdx.x * 8;
    int j = threadIdx.x;
    float bf = biasf[j], br = biasr[j];
    float af[8], ar[8];
    #pragma unroll
    for (int s = 0; s < 8; s++) { af[s] = bf; ar[s] = br; }
    for (int q = 0; q < 128; q++) {
        float4 wf = *(const float4*)(wihTq_f + q * 2048 + j * 4);
        float4 wr = *(const float4*)(wihTq_r + q * 2048 + j * 4);
        #pragma unroll
        for (int s = 0; s < 8; s++) {
            float4 xv = *(const float4*)(X + (r0 + s) * 512 + 4 * q);  // uniform
            af[s] += xv.x * wf.x + xv.y * wf.y + xv.z * wf.z + xv.w * wf.w;
            ar[s] += xv.x * wr.x + xv.y * wr.y + xv.z * wr.z + xv.w * wr.w;
        }
    }
    #pragma unroll
    for (int s = 0; s < 8; s++) {
        int r = r0 + s, b = r >> 7, ss = r & 127;
        GXF[r * 512 + j] = af[s];
        GXR[(b * 128 + (127 - ss)) * 512 + j] = ar[s];
    }
}

// ---------------- K4: BiLSTM recurrence (one block per (dir,b)) ----------------
__global__ __launch_bounds__(256, 1) void k_lstm_bi(
    const float* __restrict__ GXF, const float* __restrict__ GXR,
    const float* __restrict__ whhT_f, const float* __restrict__ whhT_r,
    float* __restrict__ HF, float* __restrict__ HR)
{
    int dir = blockIdx.x & 1, b = blockIdx.x >> 1;
    int tid = threadIdx.x, wave = tid >> 6, lane = tid & 63;
    int j1 = tid, j2 = tid + 256;
    const float* whhT = dir ? whhT_r : whhT_f;
    const float* gx = (dir ? GXR : GXF) + b * 65536;
    float* hout = (dir ? HR : HF) + b * 16384;

    float w1[128], w2[128];
    #pragma unroll
    for (int k = 0; k < 128; k++) {
        w1[k] = whhT[k * 512 + j1];
        w2[k] = whhT[k * 512 + j2];
    }
    __shared__ float hbuf[128];
    __shared__ float fo[128][2];
    float h_lo = 0.f, h_hi = 0.f, c = 0.f;
    float g1 = gx[j1], g2 = gx[j2];
    for (int t = 0; t < 128; t++) {
        float a1 = g1, a2 = g2;
        if (t < 127) { g1 = gx[(t + 1) * 512 + j1]; g2 = gx[(t + 1) * 512 + j2]; }
        #pragma unroll
        for (int k = 0; k < 64; k++) {
            float hs = rlane(h_lo, k);
            a1 += hs * w1[k];
            a2 += hs * w2[k];
        }
        #pragma unroll
        for (int k = 0; k < 64; k++) {
            float hs = rlane(h_hi, k);
            a1 += hs * w1[64 + k];
            a2 += hs * w2[64 + k];
        }
        if (wave >= 2) {
            int u = (wave - 2) * 64 + lane;
            fo[u][0] = a1;
            fo[u][1] = a2;
        }
        __syncthreads();
        if (wave < 2) {
            int u = wave * 64 + lane;
            float ig = sigf(a1);
            float gg = tanhf(a2);
            float fg = sigf(fo[u][0]);
            float og = sigf(fo[u][1]);
            c = fg * c + ig * gg;
            float hn = og * tanhf(c);
            hbuf[u] = hn;
            int tout = dir ? (127 - t) : t;
            hout[tout * 128 + u] = hn;
        }
        __syncthreads();
        h_lo = hbuf[lane];
        h_hi = hbuf[64 + lane];
    }
}

// ---------------- K5: gx2 = [hf|hr]@Wih2^T + bias2 ----------------
__global__ __launch_bounds__(512) void k_gx2(
    const float* __restrict__ HF, const float* __restrict__ HR,
    const float* __restrict__ wihT2q, const float* __restrict__ bias2,
    float* __restrict__ GX2)
{
    int r0 = blockIdx.x * 8;
    int j = threadIdx.x;
    float bb = bias2[j];
    float a[8];
    #pragma unroll
    for (int s = 0; s < 8; s++) a[s] = bb;
    for (int q = 0; q < 32; q++) {
        float4 w = *(const float4*)(wihT2q + q * 2048 + j * 4);
        #pragma unroll
        for (int s = 0; s < 8; s++) {
            int r = r0 + s;
            float4 xv = *(const float4*)(HF + r * 128 + 4 * q);  // uniform
            a[s] += xv.x * w.x + xv.y * w.y + xv.z * w.z + xv.w * w.w;
        }
    }
    for (int q = 32; q < 64; q++) {
        float4 w = *(const float4*)(wihT2q + q * 2048 + j * 4);
        #pragma unroll
        for (int s = 0; s < 8; s++) {
            int r = r0 + s;
            float4 xv = *(const float4*)(HR + r * 128 + 4 * q - 128);  // uniform
            a[s] += xv.x * w.x + xv.y * w.y + xv.z * w.z + xv.w * w.w;
        }
    }
    #pragma unroll
    for (int s = 0; s < 8; s++) GX2[(r0 + s) * 512 + j] = a[s];
}

// ---------------- K6: second LSTM recurrence + MLP head ----------------
__global__ __launch_bounds__(256, 1) void k_lstm2(
    const float* __restrict__ GX2, const float* __restrict__ whhT2,
    const float* __restrict__ denseW, const float* __restrict__ denseb,
    const float* __restrict__ clfW, const float* __restrict__ clfb,
    float* __restrict__ out)
{
    int b = blockIdx.x;
    int tid = threadIdx.x, wave = tid >> 6, lane = tid & 63;
    int j1 = tid, j2 = tid + 256;
    const float* gx = GX2 + b * 65536;

    float w1[128], w2[128];
    #pragma unroll
    for (int k = 0; k < 128; k++) {
        w1[k] = whhT2[k * 512 + j1];
        w2[k] = whhT2[k * 512 + j2];
    }
    __shared__ float hbuf[128];
    __shared__ float fo[128][2];
    float h_lo = 0.f, h_hi = 0.f, c = 0.f;
    float g1 = gx[j1], g2 = gx[j2];
    for (int t = 0; t < 128; t++) {
        float a1 = g1, a2 = g2;
        if (t < 127) { g1 = gx[(t + 1) * 512 + j1]; g2 = gx[(t + 1) * 512 + j2]; }
        #pragma unroll
        for (int k = 0; k < 64; k++) {
            float hs = rlane(h_lo, k);
            a1 += hs * w1[k];
            a2 += hs * w2[k];
        }
        #pragma unroll
        for (int k = 0; k < 64; k++) {
            float hs = rlane(h_hi, k);
            a1 += hs * w1[64 + k];
            a2 += hs * w2[64 + k];
        }
        if (wave >= 2) {
            int u = (wave - 2) * 64 + lane;
            fo[u][0] = a1;
            fo[u][1] = a2;
        }
        __syncthreads();
        if (wave < 2) {
            int u = wave * 64 + lane;
            float ig = sigf(a1);
            float gg = tanhf(a2);
            float fg = sigf(fo[u][0]);
            float og = sigf(fo[u][1]);
            c = fg * c + ig * gg;
            float hn = og * tanhf(c);
            hbuf[u] = hn;
        }
        __syncthreads();
        h_lo = hbuf[lane];
        h_hi = hbuf[64 + lane];
    }
    // head: dense(128->32) + clf(32->2)
    __shared__ float z[32];
    if (tid < 32) {
        float acc = denseb[tid];
        const float* dw = denseW + tid * 128;
        for (int k = 0; k < 128; k++) acc += hbuf[k] * dw[k];
        z[tid] = acc;
    }
    __syncthreads();
    if (tid < 2) {
        float acc = clfb[tid];
        const float* cw = clfW + tid * 32;
        #pragma unroll
        for (int m = 0; m < 32; m++) acc += z[m] * cw[m];
        out[b * 2 + tid] = acc;
    }
}

extern "C" void kernel_launch(void* const* d_in, const int* in_sizes, int n_in,
                              void* d_out, int out_size, void* d_ws, size_t ws_size,
                              hipStream_t stream) {
    const float* A     = (const float*)d_in[0];
    const float* Wx_W  = (const float*)d_in[1];
    const float* Wx_b  = (const float*)d_in[2];
    const float* Wxh_W = (const float*)d_in[3];
    const float* Wxh_b = (const float*)d_in[4];
    const float* Att_W = (const float*)d_in[5];
    const float* Att_b = (const float*)d_in[6];
    const float* Wih_f = (const float*)d_in[7];
    const float* Whh_f = (const float*)d_in[8];
    const float* bih_f = (const float*)d_in[9];
    const float* bhh_f = (const float*)d_in[10];
    const float* Wih_r = (const float*)d_in[11];
    const float* Whh_r = (const float*)d_in[12];
    const float* bih_r = (const float*)d_in[13];
    const float* bhh_r = (const float*)d_in[14];
    const float* Wih2  = (const float*)d_in[15];
    const float* Whh2  = (const float*)d_in[16];
    const float* bih2  = (const float*)d_in[17];
    const float* bhh2  = (const float*)d_in[18];
    const float* denseW = (const float*)d_in[19];
    const float* denseb = (const float*)d_in[20];
    const float* clfW   = (const float*)d_in[21];
    const float* clfb   = (const float*)d_in[22];

    float* ws = (float*)d_ws;
    float* WXb    = ws + OFF_WX;
    float* PXb    = ws + OFF_PX;
    float* Xb     = ws + OFF_X;
    float* GXF    = ws + OFF_GXF;
    float* GXR    = ws + OFF_GXR;
    float* HF     = ws + OFF_HF;
    float* HR     = ws + OFF_HR;
    float* GX2    = ws + OFF_GX2;
    float* wihTqf = ws + OFF_WIHTQ_F;
    float* wihTqr = ws + OFF_WIHTQ_R;
    float* wihT2q = ws + OFF_WIHT2Q;
    float* whhTf  = ws + OFF_WHHT_F;
    float* whhTr  = ws + OFF_WHHT_R;
    float* whhT2  = ws + OFF_WHHT2;
    float* biasf  = ws + OFF_BIASF;
    float* biasr  = ws + OFF_BIASR;
    float* bias2  = ws + OFF_BIAS2;

    k_prep<<<512, 256, 0, stream>>>(Wih_f, Wih_r, Wih2, Whh_f, Whh_r, Whh2,
                                    bih_f, bhh_f, bih_r, bhh_r, bih2, bhh2,
                                    wihTqf, wihTqr, wihT2q, whhTf, whhTr, whhT2,
                                    biasf, biasr, bias2);
    k_qk<<<B_ * S_, 64, 0, stream>>>(A, Wx_W, Wx_b, Wxh_W, Wxh_b, WXb, PXb);
    k_attn<<<B_ * (S_ / 4), 256, 0, stream>>>(A, WXb, PXb, Att_W, Att_b, Xb);
    k_gx<<<128, 512, 0, stream>>>(Xb, wihTqf, wihTqr, biasf, biasr, GXF, GXR);
    k_lstm_bi<<<16, 256, 0, stream>>>(GXF, GXR, whhTf, whhTr, HF, HR);
    k_gx2<<<128, 512, 0, stream>>>(HF, HR, wihT2q, bias2, GX2);
    k_lstm2<<<B_, 256, 0, stream>>>(GX2, whhT2, denseW, denseb, clfW, clfb,
                                    (float*)d_out);
}

// Round 2
// 513.929 us; speedup vs baseline: 1.1641x; 1.1641x over previous
//
#include <hip/hip_runtime.h>
#include <hip/hip_bf16.h>

// Sizes
#define B_ 8
#define S_ 128
#define D_ 512
#define N_ 64
#define H_ 128

// ws offsets (in floats)
#define OFF_WX      0
#define OFF_PX      65536
#define OFF_X       131072
#define OFF_GXF     655360
#define OFF_GXR     1179648
#define OFF_HF      1703936
#define OFF_HR      1835008
#define OFF_GX2     1966080
#define OFF_WIHTQ_F 2490368
#define OFF_WIHTQ_R 2752512
#define OFF_WIHT2Q  3014656
#define OFF_WHHT_F  3145728
#define OFF_WHHT_R  3211264
#define OFF_WHHT2   3276800
#define OFF_BIASF   3342336
#define OFF_BIASR   3342848
#define OFF_BIAS2   3343360

__device__ __forceinline__ float rlane(float v, int l) {
    return __int_as_float(__builtin_amdgcn_readlane(__float_as_int(v), l));
}
__device__ __forceinline__ float sigf(float x) {
    return 1.0f / (1.0f + expf(-x));
}

// ---------------- K0: weight transposes + bias sums ----------------
__global__ __launch_bounds__(256) void k_prep(
    const float* __restrict__ Wih_f, const float* __restrict__ Wih_r,
    const float* __restrict__ Wih2,
    const float* __restrict__ Whh_f, const float* __restrict__ Whh_r,
    const float* __restrict__ Whh2,
    const float* __restrict__ bih_f, const float* __restrict__ bhh_f,
    const float* __restrict__ bih_r, const float* __restrict__ bhh_r,
    const float* __restrict__ bih2, const float* __restrict__ bhh2,
    float* __restrict__ wihTq_f, float* __restrict__ wihTq_r,
    float* __restrict__ wihT2q,
    float* __restrict__ whhT_f, float* __restrict__ whhT_r,
    float* __restrict__ whhT2,
    float* __restrict__ biasf, float* __restrict__ biasr, float* __restrict__ bias2)
{
    int idx = blockIdx.x * blockDim.x + threadIdx.x;
    int stride = gridDim.x * blockDim.x;
    // Wih (512x512) -> quad-blocked transposed: out[q*2048 + j*4 + e] = in[j*512 + 4q+e]
    for (int o = idx; o < 262144; o += stride) {
        int q = o >> 11, rem = o & 2047, j = rem >> 2, e = rem & 3;
        int k = 4 * q + e;
        wihTq_f[o] = Wih_f[j * 512 + k];
        wihTq_r[o] = Wih_r[j * 512 + k];
    }
    // Wih2 (512x256)
    for (int o = idx; o < 131072; o += stride) {
        int q = o >> 11, rem = o & 2047, j = rem >> 2, e = rem & 3;
        int k = 4 * q + e;
        wihT2q[o] = Wih2[j * 256 + k];
    }
    // Whh (512x128) -> plain transpose [k][512]
    for (int o = idx; o < 65536; o += stride) {
        int k = o >> 9, j = o & 511;
        whhT_f[o] = Whh_f[j * 128 + k];
        whhT_r[o] = Whh_r[j * 128 + k];
        whhT2[o]  = Whh2[j * 128 + k];
    }
    if (idx < 512) {
        biasf[idx] = bih_f[idx] + bhh_f[idx];
        biasr[idx] = bih_r[idx] + bhh_r[idx];
        bias2[idx] = bih2[idx] + bhh2[idx];
    }
}

// ---------------- K1: Wx = A@Wx_W^T + b ; Px = A@Wxh_W^T + b ----------------
__global__ __launch_bounds__(64) void k_qk(
    const float* __restrict__ A,
    const float* __restrict__ WxW, const float* __restrict__ Wxb,
    const float* __restrict__ WxhW, const float* __restrict__ Wxhb,
    float* __restrict__ WX, float* __restrict__ PX)
{
    int bs = blockIdx.x;
    int n = threadIdx.x;
    const float* arow = A + bs * 512;
    const float* wr = WxW + n * 512;
    const float* pr = WxhW + n * 512;
    float aw = 0.f, ap = 0.f;
    #pragma unroll 8
    for (int k = 0; k < 512; k += 4) {
        float4 a = *(const float4*)(arow + k);   // uniform -> scalar loads
        float4 w = *(const float4*)(wr + k);
        float4 p = *(const float4*)(pr + k);
        aw += a.x * w.x + a.y * w.y + a.z * w.z + a.w * w.w;
        ap += a.x * p.x + a.y * p.y + a.z * p.z + a.w * p.w;
    }
    WX[bs * 64 + n] = aw + Wxb[n];
    PX[bs * 64 + n] = ap + Wxhb[n];
}

// ---------------- K2: attention scores + X = scores@A ----------------
__global__ __launch_bounds__(256) void k_attn(
    const float* __restrict__ A,
    const float* __restrict__ WX, const float* __restrict__ PX,
    const float* __restrict__ AttW, const float* __restrict__ Attb,
    float* __restrict__ X)
{
    int b = blockIdx.x >> 5;
    int i0 = (blockIdx.x & 31) * 4;
    int tid = threadIdx.x;
    __shared__ float px[128][65];
    __shared__ float wx[4][64];
    __shared__ float aw[64];
    __shared__ float sc[128][4];

    const float* pxg = PX + b * 8192;
    for (int q = tid; q < 2048; q += 256) {
        int j = q >> 4, nq = (q & 15) * 4;
        float4 v = *(const float4*)(pxg + j * 64 + nq);
        px[j][nq] = v.x; px[j][nq + 1] = v.y; px[j][nq + 2] = v.z; px[j][nq + 3] = v.w;
    }
    if (tid < 64) {
        aw[tid] = AttW[tid];
        #pragma unroll
        for (int ii = 0; ii < 4; ii++)
            wx[ii][tid] = WX[b * 8192 + (i0 + ii) * 64 + tid];
    }
    __syncthreads();
    float attb = Attb[0];
    for (int p = tid; p < 512; p += 256) {
        int ii = p >> 7, j = p & 127;
        float acc = 0.f;
        #pragma unroll 4
        for (int n = 0; n < 64; n++) {
            acc += tanhf(px[j][n] + wx[ii][n]) * aw[n];
        }
        sc[j][ii] = sigf(acc + attb);
    }
    __syncthreads();
    // X phase: 2 i-values per thread, 4 d's each
    int half = tid >> 7;
    int dq = (tid & 127) * 4;
    int ii0 = half * 2;
    float4 acc0 = {0, 0, 0, 0}, acc1 = {0, 0, 0, 0};
    const float* Ab = A + b * 65536;
    for (int j = 0; j < 128; j++) {
        float4 av = *(const float4*)(Ab + j * 512 + dq);
        float s0 = sc[j][ii0], s1 = sc[j][ii0 + 1];
        acc0.x += av.x * s0; acc0.y += av.y * s0; acc0.z += av.z * s0; acc0.w += av.w * s0;
        acc1.x += av.x * s1; acc1.y += av.y * s1; acc1.z += av.z * s1; acc1.w += av.w * s1;
    }
    float* Xp = X + b * 65536;
    *(float4*)(Xp + (i0 + ii0) * 512 + dq) = acc0;
    *(float4*)(Xp + (i0 + ii0 + 1) * 512 + dq) = acc1;
}

// ---------------- K3: gxf = X@Wih_f^T + bias ; gxr (time-reversed rows) ----------------
__global__ __launch_bounds__(512) void k_gx(
    const float* __restrict__ X,
    const float* __restrict__ wihTq_f, const float* __restrict__ wihTq_r,
    const float* __restrict__ biasf, const float* __restrict__ biasr,
    float* __restrict__ GXF, float* __restrict__ GXR)
{
    int r0 = blockIdx.x * 8;
    int j = threadIdx.x;
    float bf = biasf[j], br = biasr[j];
    float af[8], ar[8];
    #pragma unroll
    for (int s = 0; s < 8; s++) { af[s] = bf; ar[s] = br; }
    for (int q = 0; q < 128; q++) {
        float4 wf = *(const float4*)(wihTq_f + q * 2048 + j * 4);
        float4 wr = *(const float4*)(wihTq_r + q * 2048 + j * 4);
        #pragma unroll
        for (int s = 0; s < 8; s++) {
            float4 xv = *(const float4*)(X + (r0 + s) * 512 + 4 * q);  // uniform
            af[s] += xv.x * wf.x + xv.y * wf.y + xv.z * wf.z + xv.w * wf.w;
            ar[s] += xv.x * wr.x + xv.y * wr.y + xv.z * wr.z + xv.w * wr.w;
        }
    }
    #pragma unroll
    for (int s = 0; s < 8; s++) {
        int r = r0 + s, b = r >> 7, ss = r & 127;
        GXF[r * 512 + j] = af[s];
        GXR[(b * 128 + (127 - ss)) * 512 + j] = ar[s];
    }
}

// ---------------- K4: BiLSTM recurrence (one block per (dir,b), 1 gate row/thread) ----------------
__global__ __launch_bounds__(512, 2) void k_lstm_bi(
    const float* __restrict__ GXF, const float* __restrict__ GXR,
    const float* __restrict__ whhT_f, const float* __restrict__ whhT_r,
    float* __restrict__ HF, float* __restrict__ HR)
{
    int dir = blockIdx.x & 1, b = blockIdx.x >> 1;
    int j = threadIdx.x;          // gate row 0..511
    int lane = j & 63;
    const float* whhT = dir ? whhT_r : whhT_f;
    const float* gx = (dir ? GXR : GXF) + b * 65536;
    float* hout = (dir ? HR : HF) + b * 16384;

    float w[128];                 // one Whh^T column (this gate row) in registers
    #pragma unroll
    for (int k = 0; k < 128; k++) w[k] = whhT[k * 512 + j];

    __shared__ float gbuf[512];
    __shared__ float hbuf[128];
    float c = 0.f;                // meaningful only for j<128
    float h_lo = 0.f, h_hi = 0.f;
    float g = gx[j];
    for (int t = 0; t < 128; t++) {
        float a = g;
        if (t < 127) g = gx[(t + 1) * 512 + j];   // prefetch next step's gx
        #pragma unroll
        for (int k = 0; k < 64; k++) a += rlane(h_lo, k) * w[k];
        #pragma unroll
        for (int k = 0; k < 64; k++) a += rlane(h_hi, k) * w[64 + k];
        gbuf[j] = a;
        __syncthreads();
        if (j < 128) {
            float ig = sigf(a);                    // own row is the i-gate
            float fg = sigf(gbuf[128 + j]);
            float gg = tanhf(gbuf[256 + j]);
            float og = sigf(gbuf[384 + j]);
            c = fg * c + ig * gg;
            float hn = og * tanhf(c);
            hbuf[j] = hn;
            int tout = dir ? (127 - t) : t;
            hout[tout * 128 + j] = hn;
        }
        __syncthreads();
        h_lo = hbuf[lane];
        h_hi = hbuf[64 + lane];
    }
}

// ---------------- K5: gx2 = [hf|hr]@Wih2^T + bias2 ----------------
__global__ __launch_bounds__(512) void k_gx2(
    const float* __restrict__ HF, const float* __restrict__ HR,
    const float* __restrict__ wihT2q, const float* __restrict__ bias2,
    float* __restrict__ GX2)
{
    int r0 = blockIdx.x * 8;
    int j = threadIdx.x;
    float bb = bias2[j];
    float a[8];
    #pragma unroll
    for (int s = 0; s < 8; s++) a[s] = bb;
    for (int q = 0; q < 32; q++) {
        float4 w = *(const float4*)(wihT2q + q * 2048 + j * 4);
        #pragma unroll
        for (int s = 0; s < 8; s++) {
            int r = r0 + s;
            float4 xv = *(const float4*)(HF + r * 128 + 4 * q);  // uniform
            a[s] += xv.x * w.x + xv.y * w.y + xv.z * w.z + xv.w * w.w;
        }
    }
    for (int q = 32; q < 64; q++) {
        float4 w = *(const float4*)(wihT2q + q * 2048 + j * 4);
        #pragma unroll
        for (int s = 0; s < 8; s++) {
            int r = r0 + s;
            float4 xv = *(const float4*)(HR + r * 128 + 4 * q - 128);  // uniform
            a[s] += xv.x * w.x + xv.y * w.y + xv.z * w.z + xv.w * w.w;
        }
    }
    #pragma unroll
    for (int s = 0; s < 8; s++) GX2[(r0 + s) * 512 + j] = a[s];
}

// ---------------- K6: second LSTM recurrence + MLP head ----------------
__global__ __launch_bounds__(512, 2) void k_lstm2(
    const float* __restrict__ GX2, const float* __restrict__ whhT2,
    const float* __restrict__ denseW, const float* __restrict__ denseb,
    const float* __restrict__ clfW, const float* __restrict__ clfb,
    float* __restrict__ out)
{
    int b = blockIdx.x;
    int j = threadIdx.x;
    int lane = j & 63;
    const float* gx = GX2 + b * 65536;

    float w[128];
    #pragma unroll
    for (int k = 0; k < 128; k++) w[k] = whhT2[k * 512 + j];

    __shared__ float gbuf[512];
    __shared__ float hbuf[128];
    float c = 0.f;
    float h_lo = 0.f, h_hi = 0.f;
    float g = gx[j];
    for (int t = 0; t < 128; t++) {
        float a = g;
        if (t < 127) g = gx[(t + 1) * 512 + j];
        #pragma unroll
        for (int k = 0; k < 64; k++) a += rlane(h_lo, k) * w[k];
        #pragma unroll
        for (int k = 0; k < 64; k++) a += rlane(h_hi, k) * w[64 + k];
        gbuf[j] = a;
        __syncthreads();
        if (j < 128) {
            float ig = sigf(a);
            float fg = sigf(gbuf[128 + j]);
            float gg = tanhf(gbuf[256 + j]);
            float og = sigf(gbuf[384 + j]);
            c = fg * c + ig * gg;
            float hn = og * tanhf(c);
            hbuf[j] = hn;
        }
        __syncthreads();
        h_lo = hbuf[lane];
        h_hi = hbuf[64 + lane];
    }
    // head: dense(128->32) + clf(32->2); hbuf holds h[:, -1]
    __shared__ float z[32];
    if (j < 32) {
        float acc = denseb[j];
        const float* dw = denseW + j * 128;
        for (int k = 0; k < 128; k++) acc += hbuf[k] * dw[k];
        z[j] = acc;
    }
    __syncthreads();
    if (j < 2) {
        float acc = clfb[j];
        const float* cw = clfW + j * 32;
        #pragma unroll
        for (int m = 0; m < 32; m++) acc += z[m] * cw[m];
        out[b * 2 + j] = acc;
    }
}

extern "C" void kernel_launch(void* const* d_in, const int* in_sizes, int n_in,
                              void* d_out, int out_size, void* d_ws, size_t ws_size,
                              hipStream_t stream) {
    const float* A     = (const float*)d_in[0];
    const float* Wx_W  = (const float*)d_in[1];
    const float* Wx_b  = (const float*)d_in[2];
    const float* Wxh_W = (const float*)d_in[3];
    const float* Wxh_b = (const float*)d_in[4];
    const float* Att_W = (const float*)d_in[5];
    const float* Att_b = (const float*)d_in[6];
    const float* Wih_f = (const float*)d_in[7];
    const float* Whh_f = (const float*)d_in[8];
    const float* bih_f = (const float*)d_in[9];
    const float* bhh_f = (const float*)d_in[10];
    const float* Wih_r = (const float*)d_in[11];
    const float* Whh_r = (const float*)d_in[12];
    const float* bih_r = (const float*)d_in[13];
    const float* bhh_r = (const float*)d_in[14];
    const float* Wih2  = (const float*)d_in[15];
    const float* Whh2  = (const float*)d_in[16];
    const float* bih2  = (const float*)d_in[17];
    const float* bhh2  = (const float*)d_in[18];
    const float* denseW = (const float*)d_in[19];
    const float* denseb = (const float*)d_in[20];
    const float* clfW   = (const float*)d_in[21];
    const float* clfb   = (const float*)d_in[22];

    float* ws = (float*)d_ws;
    float* WXb    = ws + OFF_WX;
    float* PXb    = ws + OFF_PX;
    float* Xb     = ws + OFF_X;
    float* GXF    = ws + OFF_GXF;
    float* GXR    = ws + OFF_GXR;
    float* HF     = ws + OFF_HF;
    float* HR     = ws + OFF_HR;
    float* GX2    = ws + OFF_GX2;
    float* wihTqf = ws + OFF_WIHTQ_F;
    float* wihTqr = ws + OFF_WIHTQ_R;
    float* wihT2q = ws + OFF_WIHT2Q;
    float* whhTf  = ws + OFF_WHHT_F;
    float* whhTr  = ws + OFF_WHHT_R;
    float* whhT2  = ws + OFF_WHHT2;
    float* biasf  = ws + OFF_BIASF;
    float* biasr  = ws + OFF_BIASR;
    float* bias2  = ws + OFF_BIAS2;

    k_prep<<<512, 256, 0, stream>>>(Wih_f, Wih_r, Wih2, Whh_f, Whh_r, Whh2,
                                    bih_f, bhh_f, bih_r, bhh_r, bih2, bhh2,
                                    wihTqf, wihTqr, wihT2q, whhTf, whhTr, whhT2,
                                    biasf, biasr, bias2);
    k_qk<<<B_ * S_, 64, 0, stream>>>(A, Wx_W, Wx_b, Wxh_W, Wxh_b, WXb, PXb);
    k_attn<<<B_ * (S_ / 4), 256, 0, stream>>>(A, WXb, PXb, Att_W, Att_b, Xb);
    k_gx<<<128, 512, 0, stream>>>(Xb, wihTqf, wihTqr, biasf, biasr, GXF, GXR);
    k_lstm_bi<<<16, 512, 0, stream>>>(GXF, GXR, whhTf, whhTr, HF, HR);
    k_gx2<<<128, 512, 0, stream>>>(HF, HR, wihT2q, bias2, GX2);
    k_lstm2<<<B_, 512, 0, stream>>>(GX2, whhT2, denseW, denseb, clfW, clfb,
                                    (float*)d_out);
}

// Round 3
// 468.822 us; speedup vs baseline: 1.2761x; 1.0962x over previous
//
#include <hip/hip_runtime.h>
#include <hip/hip_bf16.h>

// Sizes
#define B_ 8
#define S_ 128
#define D_ 512
#define N_ 64
#define H_ 128

// ws offsets (in floats)
#define OFF_WX      0
#define OFF_PX      65536
#define OFF_X       131072
#define OFF_GXF     655360
#define OFF_GXR     1179648
#define OFF_HF      1703936
#define OFF_HR      1835008
#define OFF_GX2     1966080
#define OFF_WIHTQ_F 2490368
#define OFF_WIHTQ_R 2752512
#define OFF_WIHT2Q  3014656
#define OFF_BIASF   3342336
#define OFF_BIASR   3342848
#define OFF_BIAS2   3343360

__device__ __forceinline__ float rlane(float v, int l) {
    return __int_as_float(__builtin_amdgcn_readlane(__float_as_int(v), l));
}
__device__ __forceinline__ float sigf(float x) {
    return 1.0f / (1.0f + expf(-x));
}

// ---------------- K0: weight transposes + bias sums ----------------
__global__ __launch_bounds__(256) void k_prep(
    const float* __restrict__ Wih_f, const float* __restrict__ Wih_r,
    const float* __restrict__ Wih2,
    const float* __restrict__ bih_f, const float* __restrict__ bhh_f,
    const float* __restrict__ bih_r, const float* __restrict__ bhh_r,
    const float* __restrict__ bih2, const float* __restrict__ bhh2,
    float* __restrict__ wihTq_f, float* __restrict__ wihTq_r,
    float* __restrict__ wihT2q,
    float* __restrict__ biasf, float* __restrict__ biasr, float* __restrict__ bias2)
{
    int idx = blockIdx.x * blockDim.x + threadIdx.x;
    int stride = gridDim.x * blockDim.x;
    // Wih (512x512) -> quad-blocked transposed: out[q*2048 + j*4 + e] = in[j*512 + 4q+e]
    for (int o = idx; o < 262144; o += stride) {
        int q = o >> 11, rem = o & 2047, j = rem >> 2, e = rem & 3;
        int k = 4 * q + e;
        wihTq_f[o] = Wih_f[j * 512 + k];
        wihTq_r[o] = Wih_r[j * 512 + k];
    }
    // Wih2 (512x256)
    for (int o = idx; o < 131072; o += stride) {
        int q = o >> 11, rem = o & 2047, j = rem >> 2, e = rem & 3;
        int k = 4 * q + e;
        wihT2q[o] = Wih2[j * 256 + k];
    }
    if (idx < 512) {
        biasf[idx] = bih_f[idx] + bhh_f[idx];
        biasr[idx] = bih_r[idx] + bhh_r[idx];
        bias2[idx] = bih2[idx] + bhh2[idx];
    }
}

// ---------------- K1: Wx = A@Wx_W^T + b ; Px = A@Wxh_W^T + b ----------------
__global__ __launch_bounds__(64) void k_qk(
    const float* __restrict__ A,
    const float* __restrict__ WxW, const float* __restrict__ Wxb,
    const float* __restrict__ WxhW, const float* __restrict__ Wxhb,
    float* __restrict__ WX, float* __restrict__ PX)
{
    int bs = blockIdx.x;
    int n = threadIdx.x;
    const float* arow = A + bs * 512;
    const float* wr = WxW + n * 512;
    const float* pr = WxhW + n * 512;
    float aw = 0.f, ap = 0.f;
    #pragma unroll 8
    for (int k = 0; k < 512; k += 4) {
        float4 a = *(const float4*)(arow + k);   // uniform -> scalar loads
        float4 w = *(const float4*)(wr + k);
        float4 p = *(const float4*)(pr + k);
        aw += a.x * w.x + a.y * w.y + a.z * w.z + a.w * w.w;
        ap += a.x * p.x + a.y * p.y + a.z * p.z + a.w * p.w;
    }
    WX[bs * 64 + n] = aw + Wxb[n];
    PX[bs * 64 + n] = ap + Wxhb[n];
}

// ---------------- K2: attention scores + X = scores@A ----------------
__global__ __launch_bounds__(256) void k_attn(
    const float* __restrict__ A,
    const float* __restrict__ WX, const float* __restrict__ PX,
    const float* __restrict__ AttW, const float* __restrict__ Attb,
    float* __restrict__ X)
{
    int b = blockIdx.x >> 5;
    int i0 = (blockIdx.x & 31) * 4;
    int tid = threadIdx.x;
    __shared__ float px[128][65];
    __shared__ float wx[4][64];
    __shared__ float aw[64];
    __shared__ float sc[128][4];

    const float* pxg = PX + b * 8192;
    for (int q = tid; q < 2048; q += 256) {
        int j = q >> 4, nq = (q & 15) * 4;
        float4 v = *(const float4*)(pxg + j * 64 + nq);
        px[j][nq] = v.x; px[j][nq + 1] = v.y; px[j][nq + 2] = v.z; px[j][nq + 3] = v.w;
    }
    if (tid < 64) {
        aw[tid] = AttW[tid];
        #pragma unroll
        for (int ii = 0; ii < 4; ii++)
            wx[ii][tid] = WX[b * 8192 + (i0 + ii) * 64 + tid];
    }
    __syncthreads();
    float attb = Attb[0];
    for (int p = tid; p < 512; p += 256) {
        int ii = p >> 7, j = p & 127;
        float acc = 0.f;
        #pragma unroll 4
        for (int n = 0; n < 64; n++) {
            acc += tanhf(px[j][n] + wx[ii][n]) * aw[n];
        }
        sc[j][ii] = sigf(acc + attb);
    }
    __syncthreads();
    // X phase: 2 i-values per thread, 4 d's each
    int half = tid >> 7;
    int dq = (tid & 127) * 4;
    int ii0 = half * 2;
    float4 acc0 = {0, 0, 0, 0}, acc1 = {0, 0, 0, 0};
    const float* Ab = A + b * 65536;
    for (int j = 0; j < 128; j++) {
        float4 av = *(const float4*)(Ab + j * 512 + dq);
        float s0 = sc[j][ii0], s1 = sc[j][ii0 + 1];
        acc0.x += av.x * s0; acc0.y += av.y * s0; acc0.z += av.z * s0; acc0.w += av.w * s0;
        acc1.x += av.x * s1; acc1.y += av.y * s1; acc1.z += av.z * s1; acc1.w += av.w * s1;
    }
    float* Xp = X + b * 65536;
    *(float4*)(Xp + (i0 + ii0) * 512 + dq) = acc0;
    *(float4*)(Xp + (i0 + ii0 + 1) * 512 + dq) = acc1;
}

// ---------------- K3: gxf = X@Wih_f^T + bias ; gxr (time-reversed rows) ----------------
__global__ __launch_bounds__(512) void k_gx(
    const float* __restrict__ X,
    const float* __restrict__ wihTq_f, const float* __restrict__ wihTq_r,
    const float* __restrict__ biasf, const float* __restrict__ biasr,
    float* __restrict__ GXF, float* __restrict__ GXR)
{
    int r0 = blockIdx.x * 8;
    int j = threadIdx.x;
    float bf = biasf[j], br = biasr[j];
    float af[8], ar[8];
    #pragma unroll
    for (int s = 0; s < 8; s++) { af[s] = bf; ar[s] = br; }
    for (int q = 0; q < 128; q++) {
        float4 wf = *(const float4*)(wihTq_f + q * 2048 + j * 4);
        float4 wr = *(const float4*)(wihTq_r + q * 2048 + j * 4);
        #pragma unroll
        for (int s = 0; s < 8; s++) {
            float4 xv = *(const float4*)(X + (r0 + s) * 512 + 4 * q);  // uniform
            af[s] += xv.x * wf.x + xv.y * wf.y + xv.z * wf.z + xv.w * wf.w;
            ar[s] += xv.x * wr.x + xv.y * wr.y + xv.z * wr.z + xv.w * wr.w;
        }
    }
    #pragma unroll
    for (int s = 0; s < 8; s++) {
        int r = r0 + s, b = r >> 7, ss = r & 127;
        GXF[r * 512 + j] = af[s];
        GXR[(b * 128 + (127 - ss)) * 512 + j] = ar[s];
    }
}

// --- named-register weight macros: 32 float4 = 128 weight floats per thread ---
#define DECLW(q) float4 w##q = *(const float4*)(wp + (q) * 4);
#define DECLW_ALL \
    DECLW(0) DECLW(1) DECLW(2) DECLW(3) DECLW(4) DECLW(5) DECLW(6) DECLW(7) \
    DECLW(8) DECLW(9) DECLW(10) DECLW(11) DECLW(12) DECLW(13) DECLW(14) DECLW(15) \
    DECLW(16) DECLW(17) DECLW(18) DECLW(19) DECLW(20) DECLW(21) DECLW(22) DECLW(23) \
    DECLW(24) DECLW(25) DECLW(26) DECLW(27) DECLW(28) DECLW(29) DECLW(30) DECLW(31)

// one quad of the dot product; (q)<16 selects h_lo (k=0..63), else h_hi (k=64..127)
#define ACCQ(q, acc) { \
    float hv_ = ((q) < 16) ? h_lo : h_hi; \
    acc = fmaf(rlane(hv_, ((q) & 15) * 4 + 0), w##q.x, acc); \
    acc = fmaf(rlane(hv_, ((q) & 15) * 4 + 1), w##q.y, acc); \
    acc = fmaf(rlane(hv_, ((q) & 15) * 4 + 2), w##q.z, acc); \
    acc = fmaf(rlane(hv_, ((q) & 15) * 4 + 3), w##q.w, acc); }
#define ACC_ALL \
    ACCQ(0, a0) ACCQ(1, a1) ACCQ(2, a2) ACCQ(3, a3) \
    ACCQ(4, a0) ACCQ(5, a1) ACCQ(6, a2) ACCQ(7, a3) \
    ACCQ(8, a0) ACCQ(9, a1) ACCQ(10, a2) ACCQ(11, a3) \
    ACCQ(12, a0) ACCQ(13, a1) ACCQ(14, a2) ACCQ(15, a3) \
    ACCQ(16, a0) ACCQ(17, a1) ACCQ(18, a2) ACCQ(19, a3) \
    ACCQ(20, a0) ACCQ(21, a1) ACCQ(22, a2) ACCQ(23, a3) \
    ACCQ(24, a0) ACCQ(25, a1) ACCQ(26, a2) ACCQ(27, a3) \
    ACCQ(28, a0) ACCQ(29, a1) ACCQ(30, a2) ACCQ(31, a3)

// ---------------- K4: BiLSTM recurrence (one block per (dir,b), 1 gate row/thread) ----------------
__global__ __launch_bounds__(512, 2) void k_lstm_bi(
    const float* __restrict__ GXF, const float* __restrict__ GXR,
    const float* __restrict__ Whh_f, const float* __restrict__ Whh_r,
    float* __restrict__ HF, float* __restrict__ HR)
{
    int dir = blockIdx.x & 1, b = blockIdx.x >> 1;
    int j = threadIdx.x;          // gate row 0..511
    int lane = j & 63;
    const float* Whh = dir ? Whh_r : Whh_f;
    const float* gx = (dir ? GXR : GXF) + b * 65536;
    float* hout = (dir ? HR : HF) + b * 16384;

    const float* wp = Whh + j * 128;   // row j of Whh is contiguous
    DECLW_ALL

    __shared__ float gbuf[512];
    __shared__ float hbuf[128];
    float c = 0.f;                // meaningful only for j<128
    float h_lo = 0.f, h_hi = 0.f;
    float g = gx[j];
    for (int t = 0; t < 128; t++) {
        float a0 = g, a1 = 0.f, a2 = 0.f, a3 = 0.f;
        if (t < 127) g = gx[(t + 1) * 512 + j];   // prefetch next step's gx
        ACC_ALL
        gbuf[j] = (a0 + a1) + (a2 + a3);
        __syncthreads();
        if (j < 128) {
            float ig = sigf(gbuf[j]);              // own row is the i-gate
            float fg = sigf(gbuf[128 + j]);
            float gg = tanhf(gbuf[256 + j]);
            float og = sigf(gbuf[384 + j]);
            c = fg * c + ig * gg;
            float hn = og * tanhf(c);
            hbuf[j] = hn;
            int tout = dir ? (127 - t) : t;
            hout[tout * 128 + j] = hn;
        }
        __syncthreads();
        h_lo = hbuf[lane];
        h_hi = hbuf[64 + lane];
    }
}

// ---------------- K5: gx2 = [hf|hr]@Wih2^T + bias2 ----------------
__global__ __launch_bounds__(512) void k_gx2(
    const float* __restrict__ HF, const float* __restrict__ HR,
    const float* __restrict__ wihT2q, const float* __restrict__ bias2,
    float* __restrict__ GX2)
{
    int r0 = blockIdx.x * 8;
    int j = threadIdx.x;
    float bb = bias2[j];
    float a[8];
    #pragma unroll
    for (int s = 0; s < 8; s++) a[s] = bb;
    for (int q = 0; q < 32; q++) {
        float4 w = *(const float4*)(wihT2q + q * 2048 + j * 4);
        #pragma unroll
        for (int s = 0; s < 8; s++) {
            int r = r0 + s;
            float4 xv = *(const float4*)(HF + r * 128 + 4 * q);  // uniform
            a[s] += xv.x * w.x + xv.y * w.y + xv.z * w.z + xv.w * w.w;
        }
    }
    for (int q = 32; q < 64; q++) {
        float4 w = *(const float4*)(wihT2q + q * 2048 + j * 4);
        #pragma unroll
        for (int s = 0; s < 8; s++) {
            int r = r0 + s;
            float4 xv = *(const float4*)(HR + r * 128 + 4 * q - 128);  // uniform
            a[s] += xv.x * w.x + xv.y * w.y + xv.z * w.z + xv.w * w.w;
        }
    }
    #pragma unroll
    for (int s = 0; s < 8; s++) GX2[(r0 + s) * 512 + j] = a[s];
}

// ---------------- K6: second LSTM recurrence + MLP head ----------------
__global__ __launch_bounds__(512, 2) void k_lstm2(
    const float* __restrict__ GX2, const float* __restrict__ Whh2,
    const float* __restrict__ denseW, const float* __restrict__ denseb,
    const float* __restrict__ clfW, const float* __restrict__ clfb,
    float* __restrict__ out)
{
    int b = blockIdx.x;
    int j = threadIdx.x;
    int lane = j & 63;
    const float* gx = GX2 + b * 65536;

    const float* wp = Whh2 + j * 128;
    DECLW_ALL

    __shared__ float gbuf[512];
    __shared__ float hbuf[128];
    float c = 0.f;
    float h_lo = 0.f, h_hi = 0.f;
    float g = gx[j];
    for (int t = 0; t < 128; t++) {
        float a0 = g, a1 = 0.f, a2 = 0.f, a3 = 0.f;
        if (t < 127) g = gx[(t + 1) * 512 + j];
        ACC_ALL
        gbuf[j] = (a0 + a1) + (a2 + a3);
        __syncthreads();
        if (j < 128) {
            float ig = sigf(gbuf[j]);
            float fg = sigf(gbuf[128 + j]);
            float gg = tanhf(gbuf[256 + j]);
            float og = sigf(gbuf[384 + j]);
            c = fg * c + ig * gg;
            float hn = og * tanhf(c);
            hbuf[j] = hn;
        }
        __syncthreads();
        h_lo = hbuf[lane];
        h_hi = hbuf[64 + lane];
    }
    // head: dense(128->32) + clf(32->2); hbuf holds h[:, -1]
    __shared__ float z[32];
    if (j < 32) {
        float acc = denseb[j];
        const float* dw = denseW + j * 128;
        for (int k = 0; k < 128; k++) acc += hbuf[k] * dw[k];
        z[j] = acc;
    }
    __syncthreads();
    if (j < 2) {
        float acc = clfb[j];
        const float* cw = clfW + j * 32;
        #pragma unroll
        for (int m = 0; m < 32; m++) acc += z[m] * cw[m];
        out[b * 2 + j] = acc;
    }
}

extern "C" void kernel_launch(void* const* d_in, const int* in_sizes, int n_in,
                              void* d_out, int out_size, void* d_ws, size_t ws_size,
                              hipStream_t stream) {
    const float* A     = (const float*)d_in[0];
    const float* Wx_W  = (const float*)d_in[1];
    const float* Wx_b  = (const float*)d_in[2];
    const float* Wxh_W = (const float*)d_in[3];
    const float* Wxh_b = (const float*)d_in[4];
    const float* Att_W = (const float*)d_in[5];
    const float* Att_b = (const float*)d_in[6];
    const float* Wih_f = (const float*)d_in[7];
    const float* Whh_f = (const float*)d_in[8];
    const float* bih_f = (const float*)d_in[9];
    const float* bhh_f = (const float*)d_in[10];
    const float* Wih_r = (const float*)d_in[11];
    const float* Whh_r = (const float*)d_in[12];
    const float* bih_r = (const float*)d_in[13];
    const float* bhh_r = (const float*)d_in[14];
    const float* Wih2  = (const float*)d_in[15];
    const float* Whh2  = (const float*)d_in[16];
    const float* bih2  = (const float*)d_in[17];
    const float* bhh2  = (const float*)d_in[18];
    const float* denseW = (const float*)d_in[19];
    const float* denseb = (const float*)d_in[20];
    const float* clfW   = (const float*)d_in[21];
    const float* clfb   = (const float*)d_in[22];

    float* ws = (float*)d_ws;
    float* WXb    = ws + OFF_WX;
    float* PXb    = ws + OFF_PX;
    float* Xb     = ws + OFF_X;
    float* GXF    = ws + OFF_GXF;
    float* GXR    = ws + OFF_GXR;
    float* HF     = ws + OFF_HF;
    float* HR     = ws + OFF_HR;
    float* GX2    = ws + OFF_GX2;
    float* wihTqf = ws + OFF_WIHTQ_F;
    float* wihTqr = ws + OFF_WIHTQ_R;
    float* wihT2q = ws + OFF_WIHT2Q;
    float* biasf  = ws + OFF_BIASF;
    float* biasr  = ws + OFF_BIASR;
    float* bias2  = ws + OFF_BIAS2;

    k_prep<<<512, 256, 0, stream>>>(Wih_f, Wih_r, Wih2,
                                    bih_f, bhh_f, bih_r, bhh_r, bih2, bhh2,
                                    wihTqf, wihTqr, wihT2q,
                                    biasf, biasr, bias2);
    k_qk<<<B_ * S_, 64, 0, stream>>>(A, Wx_W, Wx_b, Wxh_W, Wxh_b, WXb, PXb);
    k_attn<<<B_ * (S_ / 4), 256, 0, stream>>>(A, WXb, PXb, Att_W, Att_b, Xb);
    k_gx<<<128, 512, 0, stream>>>(Xb, wihTqf, wihTqr, biasf, biasr, GXF, GXR);
    k_lstm_bi<<<16, 512, 0, stream>>>(GXF, GXR, Whh_f, Whh_r, HF, HR);
    k_gx2<<<128, 512, 0, stream>>>(HF, HR, wihT2q, bias2, GX2);
    k_lstm2<<<B_, 512, 0, stream>>>(GX2, Whh2, denseW, denseb, clfW, clfb,
                                    (float*)d_out);
}